// Round 3
// baseline (1331.405 us; speedup 1.0000x reference)
//
#include <hip/hip_runtime.h>

#define Wd 256
#define Hd 256
#define Nn 65536   // H*W
#define Cc 64
#define Vv 4
#define Bb 2
#define BVn 8
#define EPSf 1e-8f

// ---- workspace layout (bytes) ----
#define OFF_COUNT   ((size_t)0)            // u32[524288]  2 MiB
#define OFF_OFFS    ((size_t)2  << 20)     // u32[524288]  2 MiB
#define OFF_CURS    ((size_t)4  << 20)     // u32[524288]  2 MiB
#define OFF_ROWSUM  ((size_t)6  << 20)     // u32[2048]
#define OFF_ROWBASE (((size_t)6 << 20) + 65536)
#define OFF_STAGE1  ((size_t)8  << 20)     // float4[524288] 8 MiB
#define OFF_BREC    ((size_t)16 << 20)     // float4[524288] 8 MiB (x,y,z,-)
#define OFF_BFEAT   ((size_t)24 << 20)     // float[524288*64] 128 MiB
#define NEED_FULL   (OFF_BFEAT + ((size_t)BVn * Nn * Cc * 4))

// ---------------- small matrix helpers ----------------
__device__ inline void mat4_mul(const float* A, const float* B, float* C) {
#pragma unroll
  for (int i = 0; i < 4; i++)
#pragma unroll
    for (int j = 0; j < 4; j++) {
      float s = 0.f;
#pragma unroll
      for (int k = 0; k < 4; k++) s += A[i * 4 + k] * B[k * 4 + j];
      C[i * 4 + j] = s;
    }
}

__device__ inline void mat4_inv(const float* m, float* invOut) {
  float inv[16];
  inv[0] = m[5]*m[10]*m[15] - m[5]*m[11]*m[14] - m[9]*m[6]*m[15] +
           m[9]*m[7]*m[14] + m[13]*m[6]*m[11] - m[13]*m[7]*m[10];
  inv[4] = -m[4]*m[10]*m[15] + m[4]*m[11]*m[14] + m[8]*m[6]*m[15] -
           m[8]*m[7]*m[14] - m[12]*m[6]*m[11] + m[12]*m[7]*m[10];
  inv[8] = m[4]*m[9]*m[15] - m[4]*m[11]*m[13] - m[8]*m[5]*m[15] +
           m[8]*m[7]*m[13] + m[12]*m[5]*m[11] - m[12]*m[7]*m[9];
  inv[12] = -m[4]*m[9]*m[14] + m[4]*m[10]*m[13] + m[8]*m[5]*m[14] -
            m[8]*m[6]*m[13] - m[12]*m[5]*m[10] + m[12]*m[6]*m[9];
  inv[1] = -m[1]*m[10]*m[15] + m[1]*m[11]*m[14] + m[9]*m[2]*m[15] -
           m[9]*m[3]*m[14] - m[13]*m[2]*m[11] + m[13]*m[3]*m[10];
  inv[5] = m[0]*m[10]*m[15] - m[0]*m[11]*m[14] - m[8]*m[2]*m[15] +
           m[8]*m[3]*m[14] + m[12]*m[2]*m[11] - m[12]*m[3]*m[10];
  inv[9] = -m[0]*m[9]*m[15] + m[0]*m[11]*m[13] + m[8]*m[1]*m[15] -
           m[8]*m[3]*m[13] - m[12]*m[1]*m[11] + m[12]*m[3]*m[9];
  inv[13] = m[0]*m[9]*m[14] - m[0]*m[10]*m[13] - m[8]*m[1]*m[14] +
            m[8]*m[2]*m[13] + m[12]*m[1]*m[10] - m[12]*m[2]*m[9];
  inv[2] = m[1]*m[6]*m[15] - m[1]*m[7]*m[14] - m[5]*m[2]*m[15] +
           m[5]*m[3]*m[14] + m[13]*m[2]*m[7] - m[13]*m[3]*m[6];
  inv[6] = -m[0]*m[6]*m[15] + m[0]*m[7]*m[14] + m[4]*m[2]*m[15] -
           m[4]*m[3]*m[14] - m[12]*m[2]*m[7] + m[12]*m[3]*m[6];
  inv[10] = m[0]*m[5]*m[15] - m[0]*m[7]*m[13] - m[4]*m[1]*m[15] +
            m[4]*m[3]*m[13] + m[12]*m[1]*m[7] - m[12]*m[3]*m[5];
  inv[14] = -m[0]*m[5]*m[14] + m[0]*m[6]*m[13] + m[4]*m[1]*m[14] -
            m[4]*m[2]*m[13] - m[12]*m[1]*m[6] + m[12]*m[2]*m[5];
  inv[3] = -m[1]*m[6]*m[11] + m[1]*m[7]*m[10] + m[5]*m[2]*m[11] -
           m[5]*m[3]*m[10] - m[9]*m[2]*m[7] + m[9]*m[3]*m[6];
  inv[7] = m[0]*m[6]*m[11] - m[0]*m[7]*m[10] - m[4]*m[2]*m[11] +
           m[4]*m[3]*m[10] + m[8]*m[2]*m[7] - m[8]*m[3]*m[6];
  inv[11] = -m[0]*m[5]*m[11] + m[0]*m[7]*m[9] + m[4]*m[1]*m[11] -
            m[4]*m[3]*m[9] - m[8]*m[1]*m[7] + m[8]*m[3]*m[5];
  inv[15] = m[0]*m[5]*m[10] - m[0]*m[6]*m[9] - m[4]*m[1]*m[10] +
            m[4]*m[2]*m[9] + m[8]*m[1]*m[6] - m[8]*m[2]*m[5];
  float det = m[0]*inv[0] + m[1]*inv[4] + m[2]*inv[8] + m[3]*inv[12];
  det = 1.0f / det;
#pragma unroll
  for (int i = 0; i < 16; i++) invOut[i] = inv[i] * det;
}

__device__ inline void compute_T(const float* Kmat, const float* srcinv,
                                 const float* dstRT, int b, int bv, float* T) {
  float Kinv[16], M1[16], M2[16];
  mat4_inv(Kmat + b * 16, Kinv);
  mat4_mul(srcinv + bv * 16, Kinv, M1);
  mat4_mul(dstRT + b * 16, M1, M2);
  mat4_mul(Kmat + b * 16, M2, T);
}

// ---------------- K1: project, count, stage ----------------
__global__ __launch_bounds__(256) void project_count_kernel(
    const float* __restrict__ depths, const float* __restrict__ Kmat,
    const float* __restrict__ srcinv, const float* __restrict__ dstRT,
    unsigned int* __restrict__ counts, float4* __restrict__ stage1) {
  const int bv = blockIdx.x >> 8;
  const int n = ((blockIdx.x & 255) << 8) | threadIdx.x;
  const int b = bv >> 2;

  __shared__ float T[16];
  if (threadIdx.x == 0) compute_T(Kmat, srcinv, dstRT, b, bv, T);
  __syncthreads();

  const float d = depths[(size_t)bv * Nn + n];
  const float gx = (float)(n & (Wd - 1));
  const float gy = (float)(n >> 8);

  const float p0 = (T[0] * gx + T[1] * gy + T[2]) * d + T[3];
  const float p1 = (T[4] * gx + T[5] * gy + T[6]) * d + T[7];
  const float z  = (T[8] * gx + T[9] * gy + T[10]) * d + T[11];

  const float ze = z + EPSf;
  const float x = p0 / ze;
  const float y = p1 / ze;
  const float px0 = rintf(x);
  const float py0 = rintf(y);

  int bin = -1;
  if (z > EPSf && px0 >= -2.0f && px0 <= (float)(Wd + 1) &&
      py0 >= -2.0f && py0 <= (float)(Hd + 1)) {
    const int bx = min(max((int)px0, 0), Wd - 1);
    const int by = min(max((int)py0, 0), Hd - 1);
    bin = (bv << 16) | (by << 8) | bx;
    atomicAdd(&counts[bin], 1u);
  }
  float4 rec;
  rec.x = x; rec.y = y; rec.z = z; rec.w = __int_as_float(bin);
  stage1[(size_t)bv * Nn + n] = rec;
}

// ---------------- K2a: per-row sums, block per row ----------------
__global__ __launch_bounds__(256) void row_sum_kernel(
    const unsigned int* __restrict__ counts, unsigned int* __restrict__ rowsum) {
  const int r = blockIdx.x;           // 0..2047
  const int t = threadIdx.x;
  __shared__ unsigned int sh[4];
  unsigned int c = counts[(size_t)r * 256 + t];
#pragma unroll
  for (int off = 32; off >= 1; off >>= 1) c += __shfl_down(c, off, 64);
  if ((t & 63) == 0) sh[t >> 6] = c;
  __syncthreads();
  if (t == 0) rowsum[r] = sh[0] + sh[1] + sh[2] + sh[3];
}

// ---------------- K2b: exclusive scan of 2048 row sums (one block) --------
__global__ __launch_bounds__(256) void scan_rows_kernel(
    const unsigned int* __restrict__ rowsum, unsigned int* __restrict__ rowbase) {
  __shared__ unsigned int part[256];
  const int t = threadIdx.x;
  unsigned int loc[8];
  unsigned int run = 0;
#pragma unroll
  for (int i = 0; i < 8; i++) {
    loc[i] = run;
    run += rowsum[t * 8 + i];
  }
  part[t] = run;
  __syncthreads();
  for (int off = 1; off < 256; off <<= 1) {
    unsigned int x = part[t];
    unsigned int y = (t >= off) ? part[t - off] : 0u;
    __syncthreads();
    part[t] = x + y;
    __syncthreads();
  }
  const unsigned int base = (t == 0) ? 0u : part[t - 1];
#pragma unroll
  for (int i = 0; i < 8; i++) rowbase[t * 8 + i] = base + loc[i];
}

// ---------------- K2c: per-bin offsets + cursors, block per row -----------
__global__ __launch_bounds__(256) void bin_offsets_kernel(
    const unsigned int* __restrict__ counts, const unsigned int* __restrict__ rowbase,
    unsigned int* __restrict__ offs, unsigned int* __restrict__ curs) {
  const int r = blockIdx.x;           // 0..2047
  const int t = threadIdx.x;
  __shared__ unsigned int sh[256];
  const unsigned int c = counts[(size_t)r * 256 + t];
  sh[t] = c;
  __syncthreads();
  for (int off = 1; off < 256; off <<= 1) {
    unsigned int x = sh[t];
    unsigned int y = (t >= off) ? sh[t - off] : 0u;
    __syncthreads();
    sh[t] = x + y;
    __syncthreads();
  }
  const unsigned int excl = ((t == 0) ? 0u : sh[t - 1]) + rowbase[r];
  offs[(size_t)r * 256 + t] = excl;
  curs[(size_t)r * 256 + t] = excl;
}

// ---------------- K3: fill binned records + binned features ---------------
__global__ __launch_bounds__(256) void fill_kernel(
    const float4* __restrict__ stage1, const float* __restrict__ feats,
    unsigned int* __restrict__ curs, float4* __restrict__ brec,
    float4* __restrict__ bfeat) {
  const int g = blockIdx.x * 256 + threadIdx.x;  // 0..524287
  float4 rec = stage1[g];
  const int bin = __float_as_int(rec.w);
  if (bin < 0) return;
  const unsigned int slot = atomicAdd(&curs[bin], 1u);
  const int n = g & (Nn - 1);
  const int bv = g >> 16;
  brec[slot] = rec;
  const float* fp = feats + ((size_t)bv * Cc << 16) + n;
  float4* dst = bfeat + ((size_t)slot << 4);  // 16 float4 per record
#pragma unroll
  for (int q = 0; q < 16; q++) {
    float4 vv;
    vv.x = fp[(size_t)(4 * q + 0) << 16];
    vv.y = fp[(size_t)(4 * q + 1) << 16];
    vv.z = fp[(size_t)(4 * q + 2) << 16];
    vv.w = fp[(size_t)(4 * q + 3) << 16];
    dst[q] = vv;
  }
}

// ---------------- K4: gather — wave per dest pixel, lane = channel --------
__global__ __launch_bounds__(256) void gather_kernel(
    const unsigned int* __restrict__ offs, const unsigned int* __restrict__ curs,
    const float4* __restrict__ brec, const float* __restrict__ bfeat,
    float* __restrict__ out) {
  const int bv = blockIdx.x >> 14;
  const int v = (blockIdx.x >> 6) & 255;
  const int u = ((blockIdx.x & 63) << 2) | (threadIdx.x >> 6);  // 4 waves = 4 adj u
  const int lane = threadIdx.x & 63;

  float acc = 0.f, wsum = 0.f, wz = 0.f;
  const float uf = (float)u, vf = (float)v;
  const int by_lo = max(0, v - 2), by_hi = min(Hd - 1, v + 2);
  const int bx_lo = max(0, u - 2), bx_hi = min(Wd - 1, u + 2);

  for (int by = by_lo; by <= by_hi; by++) {
    const int rowb = (bv << 16) | (by << 8);
    const unsigned int s = offs[rowb + bx_lo];
    const unsigned int e = curs[rowb + bx_hi];
    for (unsigned int r = s; r < e; r++) {
      const float4 rec = brec[r];               // broadcast across wave
      const float ddx = uf - rec.x;
      const float ddy = vf - rec.y;
      const float dist = sqrtf(ddx * ddx + ddy * ddy + EPSf);
      float w = 1.0f - dist * 0.5f;             // RADIUS = 2
      if (w > 0.f) {                            // wave-uniform branch
        w *= 1.0f / (rec.z + EPSf);
        wsum += w;
        wz += w * rec.z;
        acc += w * bfeat[((size_t)r << 6) + lane];  // coalesced 256B
      }
    }
  }

  const float inv = 1.0f / (wsum + EPSf);
  const int dest = (v << 8) | u;
  float* ob = out + (((size_t)bv * 65) << 16) + dest;
  ob[(size_t)lane << 16] = acc * inv;
  if (lane == 0) ob[(size_t)Cc << 16] = wz * inv;
}

// ---------------- fallback: round-1 atomic splat (small ws) ---------------
__global__ __launch_bounds__(256) void splat_kernel(
    const float* __restrict__ feats, const float* __restrict__ depths,
    const float* __restrict__ Kmat, const float* __restrict__ srcinv,
    const float* __restrict__ dstRT, float* __restrict__ out,
    float* __restrict__ wsum) {
  const int bv = blockIdx.x >> 8;
  const int n = ((blockIdx.x & 255) << 8) | threadIdx.x;
  const int b = bv >> 2;
  __shared__ float T[16];
  if (threadIdx.x == 0) compute_T(Kmat, srcinv, dstRT, b, bv, T);
  __syncthreads();
  const float d = depths[(size_t)bv * Nn + n];
  const float gx = (float)(n & (Wd - 1));
  const float gy = (float)(n >> 8);
  const float p0 = (T[0] * gx + T[1] * gy + T[2]) * d + T[3];
  const float p1 = (T[4] * gx + T[5] * gy + T[6]) * d + T[7];
  const float z  = (T[8] * gx + T[9] * gy + T[10]) * d + T[11];
  const float ze = z + EPSf;
  const float x = p0 / ze, y = p1 / ze;
  const float zi = 1.0f / ze;
  const float px0 = rintf(x), py0 = rintf(y);
  const bool zok = (z > EPSf);
  float f[Cc];
  const float* fp = feats + (size_t)bv * Cc * Nn + n;
#pragma unroll
  for (int c = 0; c < Cc; c++) f[c] = fp[(size_t)c * Nn];
  float* outbv = out + (size_t)bv * 65 * Nn;
  float* wbv = wsum + (size_t)bv * Nn;
#pragma unroll
  for (int dy = -2; dy <= 2; dy++) {
#pragma unroll
    for (int dx = -2; dx <= 2; dx++) {
      const float px = px0 + (float)dx;
      const float py = py0 + (float)dy;
      const float ddx = px - x, ddy = py - y;
      const float dist = sqrtf(ddx * ddx + ddy * ddy + EPSf);
      float w = fmaxf(0.0f, 1.0f - dist * 0.5f);
      const bool valid = zok && (px >= 0.0f) && (px < (float)Wd) &&
                         (py >= 0.0f) && (py < (float)Hd);
      w = valid ? w * zi : 0.0f;
      if (w > 0.0f) {
        const int idx = (int)py * Wd + (int)px;
        atomicAdd(wbv + idx, w);
        atomicAdd(outbv + (size_t)Cc * Nn + idx, w * z);
#pragma unroll
        for (int c = 0; c < Cc; c++)
          atomicAdd(outbv + (size_t)c * Nn + idx, w * f[c]);
      }
    }
  }
}

__global__ __launch_bounds__(256) void norm_kernel(float* __restrict__ out,
                                                   const float* __restrict__ wsum) {
  const int t = blockIdx.x * 256 + threadIdx.x;
  const int n = t & 0xFFFF;
  const int bvc = t >> 16;
  const int bv = bvc / 65;
  const float wv = wsum[(size_t)bv * Nn + n];
  out[t] = out[t] / (wv + EPSf);
}

extern "C" void kernel_launch(void* const* d_in, const int* in_sizes, int n_in,
                              void* d_out, int out_size, void* d_ws, size_t ws_size,
                              hipStream_t stream) {
  const float* feats  = (const float*)d_in[0];
  const float* depths = (const float*)d_in[1];
  const float* Kmat   = (const float*)d_in[2];
  const float* srcinv = (const float*)d_in[4];
  const float* dstRT  = (const float*)d_in[5];
  float* out = (float*)d_out;
  char* ws = (char*)d_ws;

  if (ws_size >= NEED_FULL) {
    unsigned int* counts = (unsigned int*)(ws + OFF_COUNT);
    unsigned int* offs   = (unsigned int*)(ws + OFF_OFFS);
    unsigned int* curs   = (unsigned int*)(ws + OFF_CURS);
    unsigned int* rowsum = (unsigned int*)(ws + OFF_ROWSUM);
    unsigned int* rowbase= (unsigned int*)(ws + OFF_ROWBASE);
    float4* stage1 = (float4*)(ws + OFF_STAGE1);
    float4* brec   = (float4*)(ws + OFF_BREC);
    float4* bfeat4 = (float4*)(ws + OFF_BFEAT);
    const float* bfeat = (const float*)(ws + OFF_BFEAT);

    hipMemsetAsync(counts, 0, (size_t)BVn * Nn * sizeof(unsigned int), stream);

    project_count_kernel<<<dim3(BVn * (Nn / 256)), dim3(256), 0, stream>>>(
        depths, Kmat, srcinv, dstRT, counts, stage1);
    row_sum_kernel<<<dim3(2048), dim3(256), 0, stream>>>(counts, rowsum);
    scan_rows_kernel<<<dim3(1), dim3(256), 0, stream>>>(rowsum, rowbase);
    bin_offsets_kernel<<<dim3(2048), dim3(256), 0, stream>>>(counts, rowbase, offs, curs);
    fill_kernel<<<dim3(BVn * Nn / 256), dim3(256), 0, stream>>>(
        stage1, feats, curs, brec, bfeat4);
    gather_kernel<<<dim3(BVn * Hd * (Wd / 4)), dim3(256), 0, stream>>>(
        offs, curs, brec, bfeat, out);
  } else {
    float* wsum = (float*)ws;  // 2 MiB
    hipMemsetAsync(out, 0, (size_t)out_size * sizeof(float), stream);
    hipMemsetAsync(wsum, 0, (size_t)BVn * Nn * sizeof(float), stream);
    splat_kernel<<<dim3(BVn * (Nn / 256)), dim3(256), 0, stream>>>(
        feats, depths, Kmat, srcinv, dstRT, out, wsum);
    norm_kernel<<<dim3(BVn * 65 * Nn / 256), dim3(256), 0, stream>>>(out, wsum);
  }
}